// Round 11
// baseline (2460.044 us; speedup 1.0000x reference)
//
#include <hip/hip_runtime.h>

#define T_ 512
#define B_ 64
#define E_ 256
#define H_ 256

typedef __attribute__((ext_vector_type(8))) short short8_t;   // 8 bf16 (4 VGPRs)
typedef __attribute__((ext_vector_type(4))) float floatx4;
typedef __attribute__((ext_vector_type(4))) int intx4;        // 16 i8 (4 VGPRs)

__device__ __forceinline__ unsigned short f2bf(float f) {
  unsigned int u = __float_as_uint(f);
  u += 0x7FFFu + ((u >> 16) & 1u);           // RTNE
  return (unsigned short)(u >> 16);
}
__device__ __forceinline__ float bf2f(unsigned short s) {
  return __uint_as_float(((unsigned int)s) << 16);
}
__device__ __forceinline__ float fast_tanh(float x) {
  float e = __expf(-2.0f * x);
  return 2.0f / (1.0f + e) - 1.0f;
}

// ---------------------------------------------------------------------------
// Kernel 1: fused q/k projection (fp32; attention needs accuracy).
// ---------------------------------------------------------------------------
__global__ __launch_bounds__(256) void qk_kernel(
    const float* __restrict__ inp, const float* __restrict__ rot,
    const float* __restrict__ ent, float* __restrict__ qo, float* __restrict__ ko)
{
  __shared__ __align__(16) float As[16][136];
  __shared__ __align__(16) float B1[16][68];
  __shared__ __align__(16) float B2[16][68];
  const int tid = threadIdx.x;
  const int m0 = blockIdx.y * 128, n0 = blockIdx.x * 64;
  const int lk = tid & 15, lm = tid >> 4;
  const int ln = tid & 63, lkb = tid >> 6;
  const int tx = tid & 15, ty = tid >> 4;
  float acc1[8][4], acc2[8][4];
#pragma unroll
  for (int i = 0; i < 8; ++i)
#pragma unroll
    for (int j = 0; j < 4; ++j) { acc1[i][j] = 0.f; acc2[i][j] = 0.f; }

  for (int k0 = 0; k0 < 256; k0 += 16) {
    __syncthreads();
#pragma unroll
    for (int p = 0; p < 8; ++p) {
      int m = lm + p * 16;
      As[lk][m] = inp[(size_t)(m0 + m) * 256 + k0 + lk];
    }
#pragma unroll
    for (int p = 0; p < 4; ++p) {
      int kk = lkb + p * 4;
      B1[kk][ln] = rot[(size_t)(k0 + kk) * 256 + n0 + ln];
      B2[kk][ln] = ent[(size_t)(k0 + kk) * 256 + n0 + ln];
    }
    __syncthreads();
#pragma unroll
    for (int kk = 0; kk < 16; ++kk) {
      floatx4 a_lo = *(const floatx4*)&As[kk][ty * 8];
      floatx4 a_hi = *(const floatx4*)&As[kk][ty * 8 + 4];
      floatx4 b1v = *(const floatx4*)&B1[kk][tx * 4];
      floatx4 b2v = *(const floatx4*)&B2[kk][tx * 4];
#pragma unroll
      for (int i = 0; i < 4; ++i) {
        float alo = a_lo[i], ahi = a_hi[i];
#pragma unroll
        for (int j = 0; j < 4; ++j) {
          acc1[i][j]     += alo * b1v[j];
          acc1[i + 4][j] += ahi * b1v[j];
          acc2[i][j]     += alo * b2v[j];
          acc2[i + 4][j] += ahi * b2v[j];
        }
      }
    }
  }
#pragma unroll
  for (int i = 0; i < 8; ++i) {
    size_t row = (size_t)(m0 + ty * 8 + i);
    float4 v1 = make_float4(acc1[i][0], acc1[i][1], acc1[i][2], acc1[i][3]);
    float4 v2 = make_float4(acc2[i][0], acc2[i][1], acc2[i][2], acc2[i][3]);
    *(float4*)&qo[row * 256 + n0 + tx * 4] = v1;
    *(float4*)&ko[row * 256 + n0 + tx * 4] = v2;
  }
}

// ---------------------------------------------------------------------------
// Kernel 2: scores (NT, fp32), 128x128 tile, 8x8 acc/thread.
// ---------------------------------------------------------------------------
__global__ __launch_bounds__(256) void scores_kernel(
    const float* __restrict__ q, const float* __restrict__ k, float* __restrict__ S)
{
  __shared__ __align__(16) float As[16][136];
  __shared__ __align__(16) float Bs[16][136];
  const int tid = threadIdx.x;
  const int b = blockIdx.z;
  const int m0 = blockIdx.y * 128, n0 = blockIdx.x * 128;
  const int lk = tid & 15, lm = tid >> 4;
  const int tx = tid & 15, ty = tid >> 4;
  float acc[8][8];
#pragma unroll
  for (int i = 0; i < 8; ++i)
#pragma unroll
    for (int j = 0; j < 8; ++j) acc[i][j] = 0.f;

  const float* Ab = q + (size_t)b * 256;
  const float* Bb = k + (size_t)b * 256;
  for (int k0 = 0; k0 < 256; k0 += 16) {
    __syncthreads();
#pragma unroll
    for (int p = 0; p < 8; ++p) {
      int m = lm + p * 16;
      As[lk][m] = Ab[(size_t)(m0 + m) * 16384 + k0 + lk];
      Bs[lk][m] = Bb[(size_t)(n0 + m) * 16384 + k0 + lk];
    }
    __syncthreads();
#pragma unroll
    for (int kk = 0; kk < 16; ++kk) {
      floatx4 a_lo = *(const floatx4*)&As[kk][ty * 8];
      floatx4 a_hi = *(const floatx4*)&As[kk][ty * 8 + 4];
      floatx4 b_lo = *(const floatx4*)&Bs[kk][tx * 8];
      floatx4 b_hi = *(const floatx4*)&Bs[kk][tx * 8 + 4];
      float av[8], bv[8];
#pragma unroll
      for (int i = 0; i < 4; ++i) { av[i] = a_lo[i]; av[i + 4] = a_hi[i];
                                    bv[i] = b_lo[i]; bv[i + 4] = b_hi[i]; }
#pragma unroll
      for (int i = 0; i < 8; ++i)
#pragma unroll
        for (int j = 0; j < 8; ++j)
          acc[i][j] += av[i] * bv[j];
    }
  }
#pragma unroll
  for (int i = 0; i < 8; ++i) {
    size_t off = (size_t)b * 262144 + (size_t)(m0 + ty * 8 + i) * 512 + n0 + tx * 8;
    float4 v0 = make_float4(acc[i][0] * 0.0625f, acc[i][1] * 0.0625f,
                            acc[i][2] * 0.0625f, acc[i][3] * 0.0625f);
    float4 v1 = make_float4(acc[i][4] * 0.0625f, acc[i][5] * 0.0625f,
                            acc[i][6] * 0.0625f, acc[i][7] * 0.0625f);
    *(float4*)&S[off] = v0;
    *(float4*)&S[off + 4] = v1;
  }
}

// ---------------------------------------------------------------------------
// Kernel 3: in-place row softmax over 512 elements, 32768 rows.
// ---------------------------------------------------------------------------
__global__ __launch_bounds__(256) void softmax_kernel(float* __restrict__ S)
{
  float* p = S + (size_t)blockIdx.x * 512;
  const int tid = threadIdx.x;
  float x0 = p[tid], x1 = p[tid + 256];
  float m = fmaxf(x0, x1);
#pragma unroll
  for (int off = 32; off > 0; off >>= 1) m = fmaxf(m, __shfl_xor(m, off));
  __shared__ float red[8];
  const int wv = tid >> 6;
  if ((tid & 63) == 0) red[wv] = m;
  __syncthreads();
  m = fmaxf(fmaxf(red[0], red[1]), fmaxf(red[2], red[3]));
  float e0 = __expf(x0 - m);
  float e1 = __expf(x1 - m);
  float s = e0 + e1;
#pragma unroll
  for (int off = 32; off > 0; off >>= 1) s += __shfl_xor(s, off);
  if ((tid & 63) == 0) red[4 + wv] = s;
  __syncthreads();
  s = red[4] + red[5] + red[6] + red[7];
  float r = 1.0f / s;
  p[tid] = e0 * r;
  p[tid + 256] = e1 * r;
}

// ---------------------------------------------------------------------------
// Kernel 4: context (NN, fp32), 128x128 tile, 8x8 acc/thread.
// ---------------------------------------------------------------------------
__global__ __launch_bounds__(256) void context_kernel(
    const float* __restrict__ P, const float* __restrict__ inp, float* __restrict__ ctx)
{
  __shared__ __align__(16) float As[16][136];
  __shared__ __align__(16) float Bs[16][136];
  const int tid = threadIdx.x;
  const int b = blockIdx.z;
  const int m0 = blockIdx.y * 128, e0 = blockIdx.x * 128;
  const int lk = tid & 15, lm = tid >> 4;
  const int tx = tid & 15, ty = tid >> 4;
  const int bk = tid >> 7, be = tid & 127;
  float acc[8][8];
#pragma unroll
  for (int i = 0; i < 8; ++i)
#pragma unroll
    for (int j = 0; j < 8; ++j) acc[i][j] = 0.f;

  const float* Ab = P + (size_t)b * 262144;
  for (int k0 = 0; k0 < 512; k0 += 16) {
    __syncthreads();
#pragma unroll
    for (int p = 0; p < 8; ++p) {
      int m = lm + p * 16;
      As[lk][m] = Ab[(size_t)(m0 + m) * 512 + k0 + lk];
    }
#pragma unroll
    for (int p = 0; p < 8; ++p) {
      int kk = bk + p * 2;
      Bs[kk][be] = inp[(size_t)(k0 + kk) * 16384 + b * 256 + e0 + be];
    }
    __syncthreads();
#pragma unroll
    for (int kk = 0; kk < 16; ++kk) {
      floatx4 a_lo = *(const floatx4*)&As[kk][ty * 8];
      floatx4 a_hi = *(const floatx4*)&As[kk][ty * 8 + 4];
      floatx4 b_lo = *(const floatx4*)&Bs[kk][tx * 8];
      floatx4 b_hi = *(const floatx4*)&Bs[kk][tx * 8 + 4];
      float av[8], bv[8];
#pragma unroll
      for (int i = 0; i < 4; ++i) { av[i] = a_lo[i]; av[i + 4] = a_hi[i];
                                    bv[i] = b_lo[i]; bv[i + 4] = b_hi[i]; }
#pragma unroll
      for (int i = 0; i < 8; ++i)
#pragma unroll
        for (int j = 0; j < 8; ++j)
          acc[i][j] += av[i] * bv[j];
    }
  }
#pragma unroll
  for (int i = 0; i < 8; ++i) {
    size_t off = (size_t)(m0 + ty * 8 + i) * 16384 + (size_t)b * 256 + e0 + tx * 8;
    float4 v0 = make_float4(acc[i][0], acc[i][1], acc[i][2], acc[i][3]);
    float4 v1 = make_float4(acc[i][4], acc[i][5], acc[i][6], acc[i][7]);
    *(float4*)&ctx[off] = v0;
    *(float4*)&ctx[off + 4] = v1;
  }
}

// ---------------------------------------------------------------------------
// Kernel 5: cp[t,b,h] = bc[h] + sum_e ctx[t,b,e] Wc[e,h]   (fp32)
// ---------------------------------------------------------------------------
__global__ __launch_bounds__(256) void cp_kernel(
    const float* __restrict__ ctx, const float* __restrict__ Wc,
    const float* __restrict__ bc, float* __restrict__ cp)
{
  __shared__ __align__(16) float As[16][136];
  __shared__ __align__(16) float Bs[16][68];
  const int tid = threadIdx.x;
  const int m0 = blockIdx.y * 128, n0 = blockIdx.x * 64;
  const int lk = tid & 15, lm = tid >> 4;
  const int ln = tid & 63, lkb = tid >> 6;
  const int tx = tid & 15, ty = tid >> 4;
  float acc[8][4];
#pragma unroll
  for (int i = 0; i < 8; ++i)
#pragma unroll
    for (int j = 0; j < 4; ++j) acc[i][j] = 0.f;

  for (int k0 = 0; k0 < 256; k0 += 16) {
    __syncthreads();
#pragma unroll
    for (int p = 0; p < 8; ++p) {
      int m = lm + p * 16;
      As[lk][m] = ctx[(size_t)(m0 + m) * 256 + k0 + lk];
    }
#pragma unroll
    for (int p = 0; p < 4; ++p) {
      int kk = lkb + p * 4;
      Bs[kk][ln] = Wc[(size_t)(k0 + kk) * 256 + n0 + ln];
    }
    __syncthreads();
#pragma unroll
    for (int kk = 0; kk < 16; ++kk) {
      floatx4 a_lo = *(const floatx4*)&As[kk][ty * 8];
      floatx4 a_hi = *(const floatx4*)&As[kk][ty * 8 + 4];
      floatx4 bv = *(const floatx4*)&Bs[kk][tx * 4];
#pragma unroll
      for (int i = 0; i < 4; ++i) {
        float alo = a_lo[i], ahi = a_hi[i];
#pragma unroll
        for (int j = 0; j < 4; ++j) {
          acc[i][j]     += alo * bv[j];
          acc[i + 4][j] += ahi * bv[j];
        }
      }
    }
  }
  float b0 = bc[n0 + tx * 4 + 0], b1 = bc[n0 + tx * 4 + 1];
  float b2 = bc[n0 + tx * 4 + 2], b3 = bc[n0 + tx * 4 + 3];
#pragma unroll
  for (int i = 0; i < 8; ++i) {
    size_t row = (size_t)(m0 + ty * 8 + i);
    float4 v = make_float4(acc[i][0] + b0, acc[i][1] + b1, acc[i][2] + b2, acc[i][3] + b3);
    *(float4*)&cp[row * 256 + n0 + tx * 4] = v;
  }
}

// ---------------------------------------------------------------------------
// Kernel 6a: pack gate weights.  bf16 Wt[n][k] (for gemm_pre) as before, PLUS
// int8 Wh fragments for the scan: per column n (= g*256+H), quantize the
// recurrent rows k'=256..511 with per-column scale s = max|w|/127; write the
// bytes in MFMA B-fragment order:
//   wave w = H>>5, hi = (H>>4)&1, lm = H&15, nt = g*2+hi;
//   byte for k (0..255): kc=k>>6, qd=(k>>4)&3, b=k&15, lane=qd*16+lm
//   Wq[(((w*8+nt)*4+kc))*1024 + lane*16 + b]
// wscale[w*128+nt*16+lm] = s/127   (h-quant scale 1/127 folded in).
// ---------------------------------------------------------------------------
__global__ __launch_bounds__(256) void pack_w(
    const float* __restrict__ Wf, const float* __restrict__ Wi,
    const float* __restrict__ Wu, const float* __restrict__ Wo,
    const float* __restrict__ bfv, const float* __restrict__ biv,
    const float* __restrict__ buv, const float* __restrict__ bov,
    unsigned short* __restrict__ Wt, float* __restrict__ bcat,
    signed char* __restrict__ Wq, float* __restrict__ wscale)
{
  const int n = blockIdx.x;
  const int g = n >> 8, h = n & 255;
  const float* W = (g == 0) ? Wf : (g == 1) ? Wi : (g == 2) ? Wu : Wo;
  const float* bb = (g == 0) ? bfv : (g == 1) ? biv : (g == 2) ? buv : bov;
  const int tid = threadIdx.x;
  for (int k = tid; k < 512; k += 256)
    Wt[(size_t)n * 512 + k] = f2bf(W[(size_t)k * 256 + h]);
  if (tid == 0) bcat[n] = bb[h];

  // int8 quantization of the Wh part (k' = 256 + tid)
  float v = W[(size_t)(256 + tid) * 256 + h];
  float a = fabsf(v);
#pragma unroll
  for (int off = 32; off > 0; off >>= 1) a = fmaxf(a, __shfl_xor(a, off));
  __shared__ float mx[4];
  if ((tid & 63) == 0) mx[tid >> 6] = a;
  __syncthreads();
  float m = fmaxf(fmaxf(mx[0], mx[1]), fmaxf(mx[2], mx[3]));
  float s = fmaxf(m, 1e-12f) * (1.0f / 127.0f);
  int qv = (int)rintf(v / s);
  qv = qv < -127 ? -127 : (qv > 127 ? 127 : qv);
  const int w = h >> 5, hi = (h >> 4) & 1, lm = h & 15;
  const int nt = g * 2 + hi;
  const int kc = tid >> 6, qd = (tid >> 4) & 3, bb2 = tid & 15;
  const int lane = qd * 16 + lm;
  Wq[(size_t)(((w * 8 + nt) * 4 + kc)) * 1024 + lane * 16 + bb2] = (signed char)qv;
  if (tid == 0) wscale[w * 128 + nt * 16 + lm] = s * (1.0f / 127.0f);
}

// ---------------------------------------------------------------------------
// Kernel 6b: pre[m][n'] via bf16 MFMA; n' = h*4+g gate-interleaved (unchanged).
// ---------------------------------------------------------------------------
__global__ __launch_bounds__(256) void gemm_pre(
    const float* __restrict__ x, const float* __restrict__ cp,
    const unsigned short* __restrict__ Wt, const float* __restrict__ bcat,
    unsigned short* __restrict__ pre)
{
  __shared__ __align__(16) unsigned short As[64 * 40];
  __shared__ __align__(16) unsigned short Bs[64 * 40];
  const int tid = threadIdx.x;
  const int n0 = blockIdx.x * 64, m0 = blockIdx.y * 64;
  const int lane = tid & 63, wv = tid >> 6;
  const int lm = lane & 15, qd = lane >> 4;
  const int sr = tid >> 2, sk = (tid & 3) * 8;
  floatx4 acc[4] = {{0.f,0.f,0.f,0.f},{0.f,0.f,0.f,0.f},
                    {0.f,0.f,0.f,0.f},{0.f,0.f,0.f,0.f}};
  for (int k0 = 0; k0 < 512; k0 += 32) {
    const float* Asrc = (k0 < 256)
        ? (x  + (size_t)(m0 + sr) * 256 + k0 + sk)
        : (cp + (size_t)(m0 + sr) * 256 + (k0 - 256) + sk);
    float4 a0 = *(const float4*)Asrc;
    float4 a1 = *(const float4*)(Asrc + 4);
    short8_t av;
    av[0] = (short)f2bf(a0.x); av[1] = (short)f2bf(a0.y);
    av[2] = (short)f2bf(a0.z); av[3] = (short)f2bf(a0.w);
    av[4] = (short)f2bf(a1.x); av[5] = (short)f2bf(a1.y);
    av[6] = (short)f2bf(a1.z); av[7] = (short)f2bf(a1.w);
    short8_t bv = *(const short8_t*)&Wt[(size_t)(n0 + sr) * 512 + k0 + sk];
    *(short8_t*)&As[sr * 40 + sk] = av;
    *(short8_t*)&Bs[sr * 40 + sk] = bv;
    __syncthreads();
    short8_t af = *(const short8_t*)&As[(wv * 16 + lm) * 40 + qd * 8];
#pragma unroll
    for (int nt = 0; nt < 4; ++nt) {
      short8_t bf = *(const short8_t*)&Bs[(nt * 16 + lm) * 40 + qd * 8];
      acc[nt] = __builtin_amdgcn_mfma_f32_16x16x32_bf16(af, bf, acc[nt], 0, 0, 0);
    }
    __syncthreads();
  }
#pragma unroll
  for (int nt = 0; nt < 4; ++nt) {
    int col = n0 + nt * 16 + lm;
    float bb = bcat[col];
    int col2 = ((col & 255) << 2) | (col >> 8);
#pragma unroll
    for (int r = 0; r < 4; ++r) {
      int row = m0 + wv * 16 + qd * 4 + r;
      pre[(size_t)row * 1024 + col2] = f2bf(acc[nt][r] + bb);
    }
  }
}

// ---------------------------------------------------------------------------
// Kernel 7: LSTM scan — ZERO-EXCHANGE, int8 Wh fully CU-resident.
// 4 WGs x 512 threads (8 waves, 2/SIMD); WG bg owns batch rows [bg*16,+16).
// Wh-i8 (256 KB): kc 0-1 in VGPRs (64/thread), kc 2-3 in LDS (128 KB).
// Wave w owns h-cols [w*32,+32) x all 4 gates (nt = g*2+hi) -> each thread
// holds all 4 gates of its 2x4 cells -> in-register cell update.
// h re-quantized to i8 each step into a double-buffered LDS A-tile.
// ONE barrier/step; no spin loops -> deadlock impossible.
// ---------------------------------------------------------------------------
__global__ __launch_bounds__(512, 2) void scan_kernel(
    const unsigned short* __restrict__ pre,   // [32768][1024], col = h*4+g
    const signed char* __restrict__ Wq,       // fragment-ordered i8 Wh
    const float* __restrict__ wscale,         // [1024] folded scales
    float* __restrict__ out)
{
  __shared__ __align__(16) signed char wlds[131072];     // 128 KiB: kc 2-3 frags
  __shared__ __align__(16) signed char hq[2][16 * 272];  // 8.5 KiB h-i8 dbuf
  const int tid = threadIdx.x;
  const int bg = blockIdx.x;           // batch group 0..3 (16 rows)
  const int lane = tid & 63;
  const int w = tid >> 6;              // wave 0..7 -> h-cols [w*32, w*32+32)
  const int qd = lane >> 4;
  const int lm = lane & 15;

  // zero both h buffers (h(-1) = 0): 2*16*272 = 8704 B = 1088 u64
  {
    unsigned long long* z = (unsigned long long*)hq;
    for (int i = tid; i < 1088; i += 512) z[i] = 0ull;
  }

  // Wh fragments: kc 0,1 -> regs; kc 2,3 -> LDS
  intx4 wreg[8][2];
#pragma unroll
  for (int nt = 0; nt < 8; ++nt) {
#pragma unroll
    for (int kc = 0; kc < 4; ++kc) {
      intx4 v = *(const intx4*)&Wq[(size_t)(((w * 8 + nt) * 4 + kc)) * 1024 + lane * 16];
      if (kc < 2) wreg[nt][kc] = v;
      else *(intx4*)&wlds[w * 16384 + (nt * 2 + (kc - 2)) * 1024 + lane * 16] = v;
    }
  }
  float ws[8];
#pragma unroll
  for (int nt = 0; nt < 8; ++nt) ws[nt] = wscale[w * 128 + nt * 16 + lm];

  const unsigned long long* pq = (const unsigned long long*)pre;
  const int row0 = bg * 16 + qd * 4;            // this thread's 4 batch rows
  const int c0 = w * 32 + lm, c1 = c0 + 16;     // this thread's 2 h-cols
  unsigned long long pcur[2][4], pnext[2][4];
#pragma unroll
  for (int r = 0; r < 4; ++r) {
    pcur[0][r] = pq[(size_t)(row0 + r) * 256 + c0];
    pcur[1][r] = pq[(size_t)(row0 + r) * 256 + c1];
  }
  float cst[2][4] = {{0.f,0.f,0.f,0.f},{0.f,0.f,0.f,0.f}};

  __syncthreads();   // wlds + hq zeros visible

#pragma unroll 1
  for (int t = 0; t < 512; ++t) {
    const signed char* hR = hq[t & 1];
    signed char* hW = hq[(t + 1) & 1];

    // prefetch pre(t+1) (consumed after MFMA; a full phase of slack)
    if (t < 511) {
      size_t base = (size_t)((t + 1) * 64 + row0) * 256;
#pragma unroll
      for (int r = 0; r < 4; ++r) {
        pnext[0][r] = pq[base + (size_t)r * 256 + c0];
        pnext[1][r] = pq[base + (size_t)r * 256 + c1];
      }
    }

    // gates(16 x 64 n' per wave) = hq(16x256 i8) @ Wh-i8  (i32 accum)
    intx4 acc[8];
#pragma unroll
    for (int nt = 0; nt < 8; ++nt) acc[nt] = (intx4){0, 0, 0, 0};
#pragma unroll
    for (int kc = 0; kc < 4; ++kc) {
      intx4 av = *(const intx4*)&hR[lm * 272 + kc * 64 + qd * 16];
#pragma unroll
      for (int nt = 0; nt < 8; ++nt) {
        intx4 bv;
        if (kc < 2) bv = wreg[nt][kc];
        else bv = *(const intx4*)&wlds[w * 16384 + (nt * 2 + (kc - 2)) * 1024 + lane * 16];
        acc[nt] = __builtin_amdgcn_mfma_i32_16x16x64_i8(av, bv, acc[nt], 0, 0, 0);
      }
    }

    // epilogue: 2 h-cols x 4 rows, all 4 gates in-thread
#pragma unroll
    for (int hi = 0; hi < 2; ++hi) {
      const int col = hi ? c1 : c0;
#pragma unroll
      for (int r = 0; r < 4; ++r) {
        unsigned long long pv = pcur[hi][r];
        float xf = (float)acc[0 + hi][r] * ws[0 + hi] + bf2f((unsigned short)pv);
        float xi = (float)acc[2 + hi][r] * ws[2 + hi] + bf2f((unsigned short)(pv >> 16));
        float xu = (float)acc[4 + hi][r] * ws[4 + hi] + bf2f((unsigned short)(pv >> 32));
        float xo = (float)acc[6 + hi][r] * ws[6 + hi] + bf2f((unsigned short)(pv >> 48));
        float fg = 1.0f / (1.0f + __expf(-xf));
        float ig = 1.0f / (1.0f + __expf(-xi));
        float gg = fast_tanh(xu);
        float og = 1.0f / (1.0f + __expf(-xo));
        float cc = fg * cst[hi][r] + ig * gg;
        cst[hi][r] = cc;
        float hh = og * fast_tanh(cc);
        int hv = (int)rintf(hh * 127.0f);
        hv = hv < -127 ? -127 : (hv > 127 ? 127 : hv);
        hW[(qd * 4 + r) * 272 + col] = (signed char)hv;
        out[(size_t)t * 16384 + (size_t)(row0 + r) * 256 + col] = hh;
        if (t == 511) {
          const size_t hoff = (size_t)512 * 16384 + (size_t)(row0 + r) * 256 + col;
          out[hoff] = hh;              // hx
          out[hoff + 16384] = cc;      // cx
        }
      }
    }
#pragma unroll
    for (int r = 0; r < 4; ++r) {
      pcur[0][r] = pnext[0][r];
      pcur[1][r] = pnext[1][r];
    }
    __syncthreads();   // hW complete before next step's MFMA reads it
  }
}

// ---------------------------------------------------------------------------
extern "C" void kernel_launch(void* const* d_in, const int* in_sizes, int n_in,
                              void* d_out, int out_size, void* d_ws, size_t ws_size,
                              hipStream_t stream)
{
  const float* inputs = (const float*)d_in[0];
  const float* rot = (const float*)d_in[1];
  const float* ent = (const float*)d_in[2];
  const float* Wf = (const float*)d_in[3];
  const float* bf_ = (const float*)d_in[4];
  const float* Wi = (const float*)d_in[5];
  const float* bi_ = (const float*)d_in[6];
  const float* Wu = (const float*)d_in[7];
  const float* bu_ = (const float*)d_in[8];
  const float* Wo = (const float*)d_in[9];
  const float* bo_ = (const float*)d_in[10];
  const float* Wc = (const float*)d_in[11];
  const float* bc_ = (const float*)d_in[12];
  float* out = (float*)d_out;

  char* ws = (char*)d_ws;
  float* q  = (float*)(ws);                                   // 32 MiB [T,B,E]
  float* kb = (float*)(ws + (size_t)32 * 1024 * 1024);        // 32 MiB [T,B,E]
  float* S  = (float*)(ws + (size_t)64 * 1024 * 1024);        // 64 MiB [B,T,T]
  unsigned short* pre = (unsigned short*)S;                   // aliases S (dead)
  float* ctx = q;                                             // aliases q (dead)
  float* cp  = kb;                                            // aliases k (dead)
  // q region dead after cp_kernel -> packed weights live there
  unsigned short* Wcat = (unsigned short*)ws;                 // 1 MiB [1024][512]
  float* bcat = (float*)(ws + (size_t)1048576);               // 4 KiB
  signed char* Wq = (signed char*)(ws + (size_t)2 * 1024 * 1024);  // 256 KiB
  float* wscale = (float*)(ws + (size_t)2 * 1024 * 1024 + 262144); // 4 KiB

  qk_kernel<<<dim3(4, 256), 256, 0, stream>>>(inputs, rot, ent, q, kb);
  scores_kernel<<<dim3(4, 4, 64), 256, 0, stream>>>(q, kb, S);
  softmax_kernel<<<dim3(32768), 256, 0, stream>>>(S);
  context_kernel<<<dim3(2, 4, 64), 256, 0, stream>>>(S, inputs, ctx);
  cp_kernel<<<dim3(4, 256), 256, 0, stream>>>(ctx, Wc, bc_, cp);
  pack_w<<<dim3(1024), 256, 0, stream>>>(Wf, Wi, Wu, Wo, bf_, bi_, bu_, bo_,
                                         Wcat, bcat, Wq, wscale);
  gemm_pre<<<dim3(16, 512), 256, 0, stream>>>(inputs, cp, Wcat, bcat, pre);
  scan_kernel<<<dim3(4), 512, 0, stream>>>(pre, Wq, wscale, out);
}